// Round 13
// baseline (2057.327 us; speedup 1.0000x reference)
//
#include <hip/hip_runtime.h>

typedef float f32x4 __attribute__((ext_vector_type(4)));
typedef _Float16 f16x8 __attribute__((ext_vector_type(8)));
typedef _Float16 f16x4 __attribute__((ext_vector_type(4)));
typedef unsigned int u32x4 __attribute__((ext_vector_type(4)));

__device__ __forceinline__ unsigned short f2h_u(float f){
  union { _Float16 h; unsigned short u; } cv; cv.h = (_Float16)f; return cv.u;
}
__device__ __forceinline__ float h2f(unsigned short u){
  union { unsigned short u; _Float16 h; } cv; cv.u = u; return (float)cv.h;
}
__device__ __forceinline__ float sigmoidf_(float x){ return 1.0f / (1.0f + __expf(-x)); }

// gemmz part slab indexing
#define GP(w,b,sp) ((((w)*64 + (b))<<6) + ((sp)<<2))

// h frag loads from producer-major layout hh2[s][p][cb][4cols]
#define LOADC2(dst, c)                                                         \
  _Pragma("unroll")                                                            \
  for (int i = 0; i < 8; ++i){                                                 \
    const int p0 = pbase + (c) * 16 + (i & 1) * 8;                             \
    const int ro = ((i >> 1) * 16 + r) * 4;                                    \
    f16x4 lo_ = *(const f16x4*)(hb2 + (size_t)p0 * 256 + ro);                  \
    f16x4 hi_ = *(const f16x4*)(hb2 + (size_t)(p0 + 1) * 256 + ro);            \
    dst[i] = __builtin_shufflevector(lo_, hi_, 0, 1, 2, 3, 4, 5, 6, 7);        \
  }

#define COMPC(buf, c)                                                          \
  _Pragma("unroll")                                                            \
  for (int kk = 0; kk < 2; ++kk)                                               \
    _Pragma("unroll")                                                          \
    for (int nt = 0; nt < 2; ++nt)                                             \
      _Pragma("unroll")                                                        \
      for (int mt = 0; mt < 4; ++mt)                                           \
        acc[nt][mt] = __builtin_amdgcn_mfma_f32_16x16x32_f16(                  \
            uf[nt][(c) * 2 + kk], buf[mt * 2 + kk], acc[nt][mt], 0, 0, 0);

// ---------- conversion: x (B,S,I) f32 -> (S,B,I) f16 ----------
__global__ __launch_bounds__(256) void cvt_x(const float* __restrict__ in,
                                             unsigned short* __restrict__ out){
  int idx = blockIdx.x * 256 + threadIdx.x;
  int d4 = idx * 4;
  int s = d4 >> 16, b = (d4 >> 10) & 63, k = d4 & 1023;
  const float4 v = *(const float4*)(in + (size_t)b * 262144 + (size_t)s * 1024 + k);
  ushort4 o;
  o.x = f2h_u(v.x); o.y = f2h_u(v.y); o.z = f2h_u(v.z); o.w = f2h_u(v.w);
  *(ushort4*)(out + d4) = o;
}

struct P8 { const float* p[8]; };

__global__ __launch_bounds__(256) void cvt_w8(P8 mats, unsigned short* __restrict__ out){
  int idx = blockIdx.x * 256 + threadIdx.x;
  int e = idx * 4;
  int mi = e >> 20, off = e & 1048575;
  const float4 v = *(const float4*)(mats.p[mi] + off);
  ushort4 o;
  o.x = f2h_u(v.x); o.y = f2h_u(v.y); o.z = f2h_u(v.z); o.w = f2h_u(v.w);
  *(ushort4*)(out + e) = o;
}

__global__ __launch_bounds__(256) void pack8(P8 mats, unsigned short* __restrict__ out){
  int idx = blockIdx.x * 256 + threadIdx.x;
  int e = idx * 4;
  int j = e >> 10, k = e & 1023;
  int m = j & 7, row = j >> 3;
  const float4 v = *(const float4*)(mats.p[m] + (size_t)row * 1024 + k);
  ushort4 o;
  o.x = f2h_u(v.x); o.y = f2h_u(v.y); o.z = f2h_u(v.z); o.w = f2h_u(v.w);
  *(ushort4*)(out + e) = o;
}

// ---------- fused masked-linear GEMM (validated) + XCD-chunked swizzle ----------
__global__ __launch_bounds__(256, 2) void gemmz(
    const unsigned short* __restrict__ Xh,
    const unsigned short* __restrict__ Wg,
    unsigned short* __restrict__ Z01,
    unsigned short* __restrict__ Z23){
  const int tid = threadIdx.x, wave = tid >> 6, lane = tid & 63;
  const int r = lane & 15, q = lane >> 4;
  const int bid0 = blockIdx.x;
  const int bid = (bid0 & 7) * 2048 + (bid0 >> 3);   // bijective: 16384 % 8 == 0
  const int m0 = (bid & 255) * 64;
  const int n0 = ((bid >> 8) & 15) * 64;
  const int g  = bid >> 12;
  extern __shared__ float part[];

  const unsigned short* WL = Wg + ((size_t)(2 * g) << 20);
  const unsigned short* WM = WL + (1u << 20);

  f32x4 accL[4][4], accM[4][4];
#pragma unroll
  for (int a = 0; a < 4; ++a)
#pragma unroll
    for (int b = 0; b < 4; ++b){ accL[a][b] = 0.f; accM[a][b] = 0.f; }

  const int kb = wave * 256 + q * 8;
#pragma unroll
  for (int kk = 0; kk < 8; ++kk){
    const int k = kb + kk * 32;
    f16x8 xf[4], wl[4], wm[4];
#pragma unroll
    for (int mt = 0; mt < 4; ++mt)
      xf[mt] = *(const f16x8*)(Xh + (size_t)(m0 + mt * 16 + r) * 1024 + k);
#pragma unroll
    for (int nt = 0; nt < 4; ++nt){
      wl[nt] = *(const f16x8*)(WL + (size_t)(n0 + nt * 16 + r) * 1024 + k);
      wm[nt] = *(const f16x8*)(WM + (size_t)(n0 + nt * 16 + r) * 1024 + k);
    }
#pragma unroll
    for (int nt = 0; nt < 4; ++nt)
#pragma unroll
      for (int mt = 0; mt < 4; ++mt){
        accL[nt][mt] = __builtin_amdgcn_mfma_f32_16x16x32_f16(wl[nt], xf[mt], accL[nt][mt], 0, 0, 0);
        accM[nt][mt] = __builtin_amdgcn_mfma_f32_16x16x32_f16(wm[nt], xf[mt], accM[nt][mt], 0, 0, 0);
      }
  }

  const int ml = tid & 63, nc = tid >> 6;
  f32x4 yL[4], yM[4];
#pragma unroll
  for (int nt = 0; nt < 4; ++nt)
#pragma unroll
    for (int mt = 0; mt < 4; ++mt)
      *(f32x4*)&part[GP(wave, mt * 16 + r, ((4 * nt + q) ^ (2 * (r & 7))))] = accL[nt][mt];
  __syncthreads();
#pragma unroll
  for (int j = 0; j < 4; ++j){
    yL[j] = 0.f;
#pragma unroll
    for (int w = 0; w < 4; ++w)
      yL[j] += *(const f32x4*)&part[GP(w, ml, ((4 * nc + j) ^ (2 * (ml & 7))))];
  }
  __syncthreads();
#pragma unroll
  for (int nt = 0; nt < 4; ++nt)
#pragma unroll
    for (int mt = 0; mt < 4; ++mt)
      *(f32x4*)&part[GP(wave, mt * 16 + r, ((4 * nt + q) ^ (2 * (r & 7))))] = accM[nt][mt];
  __syncthreads();
#pragma unroll
  for (int j = 0; j < 4; ++j){
    yM[j] = 0.f;
#pragma unroll
    for (int w = 0; w < 4; ++w)
      yM[j] += *(const f32x4*)&part[GP(w, ml, ((4 * nc + j) ^ (2 * (ml & 7))))];
  }

  unsigned short* Zp = (g < 2) ? (Z01 + ((size_t)g << 24)) : (Z23 + ((size_t)(g - 2) << 24));
#pragma unroll
  for (int j = 0; j < 4; ++j){
    const int colbase = n0 + nc * 16 + j * 4;
#pragma unroll
    for (int e = 0; e < 4; ++e){
      float v = yL[j][e] * sigmoidf_(yM[j][e]);
      Zp[(size_t)(colbase + e) * 16384 + m0 + ml] = f2h_u(v);
    }
  }
}

// ---------- recurrence: fully per-wave decoupled barrier ----------
// flags[bi] = one 128B line; dword w = step count signalled by wave w of block bi.
// Consumer wave w depends exactly on producer blocks [64w, 64w+64): lane l polls
// producer (64w+l)'s 4 wave-flags with one dwordx4. Producer wave stores its
// 128B h line, drains, signals its own flag. Only 2 block barriers/step (LDS).
__global__ __launch_bounds__(256, 1) void lstm_rec(
    const unsigned short* __restrict__ zF, const unsigned short* __restrict__ zI,
    const unsigned short* __restrict__ zO, const unsigned short* __restrict__ zC,
    const unsigned short* __restrict__ Ug,
    const float* __restrict__ bF, const float* __restrict__ bI,
    const float* __restrict__ bO, const float* __restrict__ bC,
    unsigned short* __restrict__ hh2,        // [256][256][64][4] f16
    unsigned int* __restrict__ flags,        // [256][32] (line per block, 4 used)
    float* __restrict__ out){
  const int tid = threadIdx.x, wave = tid >> 6, lane = tid & 63;
  const int bi = blockIdx.x, n0 = bi * 4, j0 = bi * 32;
  const int r = lane & 15, q = lane >> 4;
  const int pbase = wave * 64 + 2 * q;             // data-producer base
  const unsigned int* fpoll = flags + (size_t)(wave * 64 + lane) * 32;
  const unsigned int* fsig  = flags + (size_t)bi * 32 + wave;
  __shared__ __align__(16) float part[4][64][36];

  f16x8 uf[2][8];
#pragma unroll
  for (int nt = 0; nt < 2; ++nt)
#pragma unroll
    for (int kk = 0; kk < 8; ++kk)
      uf[nt][kk] = *(const f16x8*)(Ug + (size_t)(j0 + nt * 16 + r) * 1024 + wave * 256 + kk * 32 + q * 8);

  const int cb = tid >> 2, cl = tid & 3;
  const float bFv = bF[n0 + cl], bIv = bI[n0 + cl], bOv = bO[n0 + cl], bCv = bC[n0 + cl];
  const size_t zb = (size_t)(n0 + cl) * 16384 + cb;
  float c_reg = 0.f;

#pragma unroll 1
  for (int s = 0; s < 256; ++s){
    float zf = h2f(zF[zb + s * 64]);
    float zi = h2f(zI[zb + s * 64]);
    float zo = h2f(zO[zb + s * 64]);
    float zc = h2f(zC[zb + s * 64]);

    f32x4 acc[2][4];
#pragma unroll
    for (int nt = 0; nt < 2; ++nt)
#pragma unroll
      for (int mt = 0; mt < 4; ++mt) acc[nt][mt] = 0.f;

    if (s > 0){
      const unsigned tgt = (unsigned)s;
      // per-wave poll: this wave's 64 producers, 4 wave-flags each
      for (;;){
        u32x4 fv;
        asm volatile("global_load_dwordx4 %0, %1, off sc0 sc1\n\t"
                     "s_waitcnt vmcnt(0)"
                     : "=v"(fv) : "v"(fpoll) : "memory");
        int ok = (fv[0] >= tgt) & (fv[1] >= tgt) & (fv[2] >= tgt) & (fv[3] >= tgt);
        if (__all(ok)) break;
      }
      // no __syncthreads: this wave's data deps are exactly its polled producers
      const unsigned short* hb2 = hh2 + (size_t)(s - 1) * 65536;
      f16x8 hA[8], hB[8];
      LOADC2(hA, 0);
      LOADC2(hB, 1);
      COMPC(hA, 0);
      LOADC2(hA, 2);
      COMPC(hB, 1);
      LOADC2(hB, 3);
      COMPC(hA, 2);
      COMPC(hB, 3);
    }

#pragma unroll
    for (int nt = 0; nt < 2; ++nt)
#pragma unroll
      for (int mt = 0; mt < 4; ++mt)
        *(f32x4*)&part[wave][mt * 16 + r][nt * 16 + q * 4] = acc[nt][mt];
    __syncthreads();

    f32x4 y0 = 0.f, y1 = 0.f;
#pragma unroll
    for (int w = 0; w < 4; ++w){
      y0 += *(const f32x4*)&part[w][cb][cl * 8];
      y1 += *(const f32x4*)&part[w][cb][cl * 8 + 4];
    }
    __syncthreads();   // protects part reuse at next step (no tail barrier anymore)

    float fg = sigmoidf_(zf + y0[0] * sigmoidf_(y0[1]) + bFv);
    float ig = sigmoidf_(zi + y0[2] * sigmoidf_(y0[3]) + bIv);
    float og = sigmoidf_(zo + y1[0] * sigmoidf_(y1[1]) + bOv);
    float cg = tanhf   (zc + y1[2] * sigmoidf_(y1[3]) + bCv);
    c_reg = cg * ig + fg * c_reg;
    float h = og * c_reg;

    // wave's h line (its 16 batches x 4 cols = 128B), write-through LLC
    float hn = __shfl_xor(h, 1);
    if (!(cl & 1)){
      unsigned int pv = (unsigned)f2h_u(h) | ((unsigned)f2h_u(hn) << 16);
      const unsigned short* hw = hh2 + (size_t)s * 65536 + bi * 256 + cb * 4 + cl;
      asm volatile("global_store_dword %0, %1, off sc0 sc1" :: "v"(hw), "v"(pv) : "memory");
    }
    if (s == 255){
      out[16777216 + cb * 1024 + n0 + cl] = h;
      out[16777216 + 65536 + cb * 1024 + n0 + cl] = c_reg;
      break;
    }
    // per-wave drain + per-wave signal (no block sync)
    asm volatile("s_waitcnt vmcnt(0)" ::: "memory");
    if ((tid & 63) == 0){
      unsigned int v = (unsigned)(s + 1);
      asm volatile("global_store_dword %0, %1, off sc0 sc1" :: "v"(fsig), "v"(v) : "memory");
    }
  }
}

// ---------- expand hh2 (producer-major) -> out (B,S,H f32) ----------
__global__ __launch_bounds__(256) void expand_out(const unsigned short* __restrict__ hh2,
                                                  float* __restrict__ out){
  int idx = blockIdx.x * 256 + threadIdx.x;      // 4,194,304 threads
  int p = idx & 255, s = (idx >> 8) & 255, cb = idx >> 16;
  f16x4 v = *(const f16x4*)(hh2 + (size_t)s * 65536 + p * 256 + cb * 4);
  float4 f = { (float)v[0], (float)v[1], (float)v[2], (float)v[3] };
  *(float4*)(out + ((size_t)cb * 256 + s) * 1024 + p * 4) = f;
}

// ---------- host launch ----------
extern "C" void kernel_launch(void* const* d_in, const int* in_sizes, int n_in,
                              void* d_out, int out_size, void* d_ws, size_t ws_size,
                              hipStream_t stream){
  (void)in_sizes; (void)n_in; (void)out_size; (void)ws_size;
  char* ws = (char*)d_ws;
  const float* bF = (const float*)d_in[17];
  const float* bI = (const float*)d_in[18];
  const float* bO = (const float*)d_in[19];
  const float* bC = (const float*)d_in[20];
  float* outp = (float*)d_out;
  P8 w8, u8;
  for (int m = 0; m < 8; ++m){
    w8.p[m] = (const float*)d_in[1 + m];
    u8.p[m] = (const float*)d_in[9 + m];
  }

  unsigned short* xh  = (unsigned short*)(ws);               // 33,554,432 B
  unsigned short* wg  = (unsigned short*)(ws + 33554432);    // 16,777,216 B
  unsigned short* ug  = (unsigned short*)(ws + 50331648);    // 16,777,216 B
  unsigned short* z23 = (unsigned short*)(ws + 67108864);    // 67,108,864 B
  unsigned short* hh2 = (unsigned short*)(ws + 134217728);   // 33,554,432 B
  unsigned int* flags = (unsigned int*)  (ws + 167772160);   //     32,768 B (padded)
  unsigned short* z01 = (unsigned short*)d_out;              // zT_f, zT_i

  (void)hipMemsetAsync(flags, 0, 32768, stream);
  cvt_x<<<16384, 256, 0, stream>>>((const float*)d_in[0], xh);
  cvt_w8<<<8192, 256, 0, stream>>>(w8, wg);
  pack8<<<8192, 256, 0, stream>>>(u8, ug);
  gemmz<<<16384, 256, 65536, stream>>>(xh, wg, z01, z23);

  const unsigned short* zF = z01;
  const unsigned short* zI = z01 + 16777216;
  const unsigned short* zO = z23;
  const unsigned short* zC = z23 + 16777216;

  void* args[] = { (void*)&zF, (void*)&zI, (void*)&zO, (void*)&zC, (void*)&ug,
                   (void*)&bF, (void*)&bI, (void*)&bO, (void*)&bC,
                   (void*)&hh2, (void*)&flags, (void*)&outp };
  if (hipLaunchCooperativeKernel((const void*)lstm_rec, dim3(256), dim3(256), args, 0u, stream) != hipSuccess)
    lstm_rec<<<256, 256, 0, stream>>>(zF, zI, zO, zC, ug, bF, bI, bO, bC, hh2, flags, outp);

  expand_out<<<16384, 256, 0, stream>>>(hh2, outp);
}

// Round 14
// 1495.123 us; speedup vs baseline: 1.3760x; 1.3760x over previous
//
#include <hip/hip_runtime.h>

typedef float f32x4 __attribute__((ext_vector_type(4)));
typedef _Float16 f16x8 __attribute__((ext_vector_type(8)));
typedef _Float16 f16x4 __attribute__((ext_vector_type(4)));

typedef const __attribute__((address_space(1))) unsigned int* gptr_t;
typedef __attribute__((address_space(3))) unsigned int* lptr_t;

__device__ __forceinline__ unsigned short f2h_u(float f){
  union { _Float16 h; unsigned short u; } cv; cv.h = (_Float16)f; return cv.u;
}
__device__ __forceinline__ float h2f(unsigned short u){
  union { unsigned short u; _Float16 h; } cv; cv.u = u; return (float)cv.h;
}
__device__ __forceinline__ float sigmoidf_(float x){ return 1.0f / (1.0f + __expf(-x)); }

// h frag loads from producer-major layout hh2[s][p][cb][4cols]
#define LOADC2(dst, c)                                                         \
  _Pragma("unroll")                                                            \
  for (int i = 0; i < 8; ++i){                                                 \
    const int p0 = pbase + (c) * 16 + (i & 1) * 8;                             \
    const int ro = ((i >> 1) * 16 + r) * 4;                                    \
    f16x4 lo_ = *(const f16x4*)(hb2 + (size_t)p0 * 256 + ro);                  \
    f16x4 hi_ = *(const f16x4*)(hb2 + (size_t)(p0 + 1) * 256 + ro);            \
    dst[i] = __builtin_shufflevector(lo_, hi_, 0, 1, 2, 3, 4, 5, 6, 7);        \
  }

#define COMPC(buf, c)                                                          \
  _Pragma("unroll")                                                            \
  for (int kk = 0; kk < 2; ++kk)                                               \
    _Pragma("unroll")                                                          \
    for (int nt = 0; nt < 2; ++nt)                                             \
      _Pragma("unroll")                                                        \
      for (int mt = 0; mt < 4; ++mt)                                           \
        acc[nt][mt] = __builtin_amdgcn_mfma_f32_16x16x32_f16(                  \
            uf[nt][(c) * 2 + kk], buf[mt * 2 + kk], acc[nt][mt], 0, 0, 0);

// ---------- conversion: x (B,S,I) f32 -> (S,B,I) f16 ----------
__global__ __launch_bounds__(256) void cvt_x(const float* __restrict__ in,
                                             unsigned short* __restrict__ out){
  int idx = blockIdx.x * 256 + threadIdx.x;
  int d4 = idx * 4;
  int s = d4 >> 16, b = (d4 >> 10) & 63, k = d4 & 1023;
  const float4 v = *(const float4*)(in + (size_t)b * 262144 + (size_t)s * 1024 + k);
  ushort4 o;
  o.x = f2h_u(v.x); o.y = f2h_u(v.y); o.z = f2h_u(v.z); o.w = f2h_u(v.w);
  *(ushort4*)(out + d4) = o;
}

struct P8 { const float* p[8]; };

__global__ __launch_bounds__(256) void cvt_w8(P8 mats, unsigned short* __restrict__ out){
  int idx = blockIdx.x * 256 + threadIdx.x;
  int e = idx * 4;
  int mi = e >> 20, off = e & 1048575;
  const float4 v = *(const float4*)(mats.p[mi] + off);
  ushort4 o;
  o.x = f2h_u(v.x); o.y = f2h_u(v.y); o.z = f2h_u(v.z); o.w = f2h_u(v.w);
  *(ushort4*)(out + e) = o;
}

__global__ __launch_bounds__(256) void pack8(P8 mats, unsigned short* __restrict__ out){
  int idx = blockIdx.x * 256 + threadIdx.x;
  int e = idx * 4;
  int j = e >> 10, k = e & 1023;
  int m = j & 7, row = j >> 3;
  const float4 v = *(const float4*)(mats.p[m] + (size_t)row * 1024 + k);
  ushort4 o;
  o.x = f2h_u(v.x); o.y = f2h_u(v.y); o.z = f2h_u(v.z); o.w = f2h_u(v.w);
  *(ushort4*)(out + e) = o;
}

// ---------- m97-style dual-B masked-linear GEMM ----------
// 128x128 tile, BK=32, 4 waves (2x2 quadrants of 64x64), LDS staging via
// global_load_lds(16B) with both-sides XOR slot swizzle. Output: transposed
// planes zT_g[n][m] = (X@W^T * sigmoid(X@Wm^T)) as f16, direct 8B stores.
__global__ __launch_bounds__(256, 2) void gemmz(
    const unsigned short* __restrict__ Xh,   // [16384][1024] f16
    const unsigned short* __restrict__ Wg,   // [8][1024][1024] f16
    unsigned short* __restrict__ Z01,
    unsigned short* __restrict__ Z23){
  __shared__ unsigned short As[128 * 32];
  __shared__ unsigned short Bl[128 * 32];
  __shared__ unsigned short Bm[128 * 32];
  const int tid = threadIdx.x;
  const int wave = tid >> 6, lane = tid & 63;
  const int r = lane & 15, q = lane >> 4;
  const int bid0 = blockIdx.x;
  const int bid = (bid0 & 7) * 512 + (bid0 >> 3);  // XCD-chunked, bijective (4096%8==0)
  const int m0 = (bid & 127) * 128;
  const int n0 = ((bid >> 7) & 7) * 128;
  const int g  = bid >> 10;
  const int wm = wave >> 1, wn = wave & 1;

  const unsigned short* WL = Wg + ((size_t)(2 * g) << 20);
  const unsigned short* WM = WL + (1u << 20);

  f32x4 accL[4][4], accM[4][4];
#pragma unroll
  for (int a = 0; a < 4; ++a)
#pragma unroll
    for (int b = 0; b < 4; ++b){ accL[a][b] = 0.f; accM[a][b] = 0.f; }

  const int st_rl = lane >> 2;            // row-local within 16-row chunk
  const int st_s0 = lane & 3;             // lds slot

  for (int kt = 0; kt < 32; ++kt){
    const int k0 = kt * 32;
#pragma unroll
    for (int j = 0; j < 2; ++j){
      const int c = wave * 2 + j;
      const int row = c * 16 + st_rl;
      const int slot = st_s0 ^ ((row >> 1) & 3);
      const unsigned short* sA = Xh + (size_t)(m0 + row) * 1024 + k0 + slot * 8;
      const unsigned short* sL = WL + (size_t)(n0 + row) * 1024 + k0 + slot * 8;
      const unsigned short* sM = WM + (size_t)(n0 + row) * 1024 + k0 + slot * 8;
      __builtin_amdgcn_global_load_lds((gptr_t)sA, (lptr_t)(As + c * 512), 16, 0, 0);
      __builtin_amdgcn_global_load_lds((gptr_t)sL, (lptr_t)(Bl + c * 512), 16, 0, 0);
      __builtin_amdgcn_global_load_lds((gptr_t)sM, (lptr_t)(Bm + c * 512), 16, 0, 0);
    }
    __syncthreads();

    f16x8 af[4], bl[4], bm[4];
#pragma unroll
    for (int mt = 0; mt < 4; ++mt){
      const int row = wm * 64 + mt * 16 + r;
      const int slot = q ^ ((row >> 1) & 3);
      af[mt] = *(const f16x8*)(As + row * 32 + slot * 8);
    }
#pragma unroll
    for (int nt = 0; nt < 4; ++nt){
      const int row = wn * 64 + nt * 16 + r;
      const int slot = q ^ ((row >> 1) & 3);
      bl[nt] = *(const f16x8*)(Bl + row * 32 + slot * 8);
      bm[nt] = *(const f16x8*)(Bm + row * 32 + slot * 8);
    }
#pragma unroll
    for (int nt = 0; nt < 4; ++nt)
#pragma unroll
      for (int mt = 0; mt < 4; ++mt){
        accL[mt][nt] = __builtin_amdgcn_mfma_f32_16x16x32_f16(af[mt], bl[nt], accL[mt][nt], 0, 0, 0);
        accM[mt][nt] = __builtin_amdgcn_mfma_f32_16x16x32_f16(af[mt], bm[nt], accM[mt][nt], 0, 0, 0);
      }
    __syncthreads();
  }

  // epilogue: V[mt][nt][rg] = Z[m0+wm*64+mt*16+q*4+rg][n0+wn*64+nt*16+r]
  // -> zT[n][m..m+3]: one 8B store per fragment per lane
  unsigned short* Zp = (g < 2) ? (Z01 + ((size_t)g << 24)) : (Z23 + ((size_t)(g - 2) << 24));
#pragma unroll
  for (int mt = 0; mt < 4; ++mt)
#pragma unroll
    for (int nt = 0; nt < 4; ++nt){
      f32x4 aL = accL[mt][nt], aM = accM[mt][nt];
      union { ushort4 u; uint2 d; } o;
      o.u.x = f2h_u(aL[0] * sigmoidf_(aM[0]));
      o.u.y = f2h_u(aL[1] * sigmoidf_(aM[1]));
      o.u.z = f2h_u(aL[2] * sigmoidf_(aM[2]));
      o.u.w = f2h_u(aL[3] * sigmoidf_(aM[3]));
      const int gn = n0 + wn * 64 + nt * 16 + r;
      const int gm = m0 + wm * 64 + mt * 16 + q * 4;
      *(uint2*)(Zp + (size_t)gn * 16384 + gm) = o.d;
    }
}

// ---------- recurrence: round-12 validated (padded per-line flags) ----------
__global__ __launch_bounds__(256, 1) void lstm_rec(
    const unsigned short* __restrict__ zF, const unsigned short* __restrict__ zI,
    const unsigned short* __restrict__ zO, const unsigned short* __restrict__ zC,
    const unsigned short* __restrict__ Ug,
    const float* __restrict__ bF, const float* __restrict__ bI,
    const float* __restrict__ bO, const float* __restrict__ bC,
    unsigned short* __restrict__ hh2,        // [256][256][64][4] f16
    unsigned int* __restrict__ flags,        // [256] padded: one 128B line each
    float* __restrict__ out){
  const int tid = threadIdx.x, wave = tid >> 6, lane = tid & 63;
  const int bi = blockIdx.x, n0 = bi * 4, j0 = bi * 32;
  const int r = lane & 15, q = lane >> 4;
  const int pbase = wave * 64 + 2 * q;
  __shared__ __align__(16) float part[4][64][36];

  const unsigned int* f0 = flags + (size_t)lane * 32;
  const unsigned int* f1 = flags + (size_t)(lane + 64) * 32;
  const unsigned int* f2 = flags + (size_t)(lane + 128) * 32;
  const unsigned int* f3 = flags + (size_t)(lane + 192) * 32;

  f16x8 uf[2][8];
#pragma unroll
  for (int nt = 0; nt < 2; ++nt)
#pragma unroll
    for (int kk = 0; kk < 8; ++kk)
      uf[nt][kk] = *(const f16x8*)(Ug + (size_t)(j0 + nt * 16 + r) * 1024 + wave * 256 + kk * 32 + q * 8);

  const int cb = tid >> 2, cl = tid & 3;
  const float bFv = bF[n0 + cl], bIv = bI[n0 + cl], bOv = bO[n0 + cl], bCv = bC[n0 + cl];
  const size_t zb = (size_t)(n0 + cl) * 16384 + cb;
  float c_reg = 0.f;

#pragma unroll 1
  for (int s = 0; s < 256; ++s){
    float zf = h2f(zF[zb + s * 64]);
    float zi = h2f(zI[zb + s * 64]);
    float zo = h2f(zO[zb + s * 64]);
    float zc = h2f(zC[zb + s * 64]);

    f32x4 acc[2][4];
#pragma unroll
    for (int nt = 0; nt < 2; ++nt)
#pragma unroll
      for (int mt = 0; mt < 4; ++mt) acc[nt][mt] = 0.f;

    if (s > 0){
      const unsigned tgt = (unsigned)s;
      if (wave == 0){
        for (;;){
          unsigned a, b, c, d;
          asm volatile("global_load_dword %0, %1, off sc0 sc1" : "=v"(a) : "v"(f0) : "memory");
          asm volatile("global_load_dword %0, %1, off sc0 sc1" : "=v"(b) : "v"(f1) : "memory");
          asm volatile("global_load_dword %0, %1, off sc0 sc1" : "=v"(c) : "v"(f2) : "memory");
          asm volatile("global_load_dword %0, %1, off sc0 sc1" : "=v"(d) : "v"(f3) : "memory");
          asm volatile("s_waitcnt vmcnt(0)" ::: "memory");
          int ok = (a >= tgt) & (b >= tgt) & (c >= tgt) & (d >= tgt);
          if (__all(ok)) break;
        }
      }
      __syncthreads();

      const unsigned short* hb2 = hh2 + (size_t)(s - 1) * 65536;
      f16x8 hA[8], hB[8];
      LOADC2(hA, 0);
      LOADC2(hB, 1);
      COMPC(hA, 0);
      LOADC2(hA, 2);
      COMPC(hB, 1);
      LOADC2(hB, 3);
      COMPC(hA, 2);
      COMPC(hB, 3);
    }

#pragma unroll
    for (int nt = 0; nt < 2; ++nt)
#pragma unroll
      for (int mt = 0; mt < 4; ++mt)
        *(f32x4*)&part[wave][mt * 16 + r][nt * 16 + q * 4] = acc[nt][mt];
    __syncthreads();

    f32x4 y0 = 0.f, y1 = 0.f;
#pragma unroll
    for (int w = 0; w < 4; ++w){
      y0 += *(const f32x4*)&part[w][cb][cl * 8];
      y1 += *(const f32x4*)&part[w][cb][cl * 8 + 4];
    }

    float fg = sigmoidf_(zf + y0[0] * sigmoidf_(y0[1]) + bFv);
    float ig = sigmoidf_(zi + y0[2] * sigmoidf_(y0[3]) + bIv);
    float og = sigmoidf_(zo + y1[0] * sigmoidf_(y1[1]) + bOv);
    float cg = tanhf   (zc + y1[2] * sigmoidf_(y1[3]) + bCv);
    c_reg = cg * ig + fg * c_reg;
    float h = og * c_reg;

    float hn = __shfl_xor(h, 1);
    if (!(cl & 1)){
      unsigned int pv = (unsigned)f2h_u(h) | ((unsigned)f2h_u(hn) << 16);
      const unsigned short* hw = hh2 + (size_t)s * 65536 + bi * 256 + cb * 4 + cl;
      asm volatile("global_store_dword %0, %1, off sc0 sc1" :: "v"(hw), "v"(pv) : "memory");
    }
    if (s == 255){
      out[16777216 + cb * 1024 + n0 + cl] = h;
      out[16777216 + 65536 + cb * 1024 + n0 + cl] = c_reg;
      break;
    }
    asm volatile("s_waitcnt vmcnt(0)" ::: "memory");
    __syncthreads();
    if (tid == 0){
      unsigned int v = (unsigned)(s + 1);
      const unsigned int* fw = flags + (size_t)bi * 32;
      asm volatile("global_store_dword %0, %1, off sc0 sc1" :: "v"(fw), "v"(v) : "memory");
    }
  }
}

// ---------- expand hh2 (producer-major) -> out (B,S,H f32) ----------
__global__ __launch_bounds__(256) void expand_out(const unsigned short* __restrict__ hh2,
                                                  float* __restrict__ out){
  int idx = blockIdx.x * 256 + threadIdx.x;
  int p = idx & 255, s = (idx >> 8) & 255, cb = idx >> 16;
  f16x4 v = *(const f16x4*)(hh2 + (size_t)s * 65536 + p * 256 + cb * 4);
  float4 f = { (float)v[0], (float)v[1], (float)v[2], (float)v[3] };
  *(float4*)(out + ((size_t)cb * 256 + s) * 1024 + p * 4) = f;
}

// ---------- host launch ----------
extern "C" void kernel_launch(void* const* d_in, const int* in_sizes, int n_in,
                              void* d_out, int out_size, void* d_ws, size_t ws_size,
                              hipStream_t stream){
  (void)in_sizes; (void)n_in; (void)out_size; (void)ws_size;
  char* ws = (char*)d_ws;
  const float* bF = (const float*)d_in[17];
  const float* bI = (const float*)d_in[18];
  const float* bO = (const float*)d_in[19];
  const float* bC = (const float*)d_in[20];
  float* outp = (float*)d_out;
  P8 w8, u8;
  for (int m = 0; m < 8; ++m){
    w8.p[m] = (const float*)d_in[1 + m];
    u8.p[m] = (const float*)d_in[9 + m];
  }

  unsigned short* xh  = (unsigned short*)(ws);               // 33,554,432 B
  unsigned short* wg  = (unsigned short*)(ws + 33554432);    // 16,777,216 B
  unsigned short* ug  = (unsigned short*)(ws + 50331648);    // 16,777,216 B
  unsigned short* z23 = (unsigned short*)(ws + 67108864);    // 67,108,864 B
  unsigned short* hh2 = (unsigned short*)(ws + 134217728);   // 33,554,432 B
  unsigned int* flags = (unsigned int*)  (ws + 167772160);   //     32,768 B (padded)
  unsigned short* z01 = (unsigned short*)d_out;              // zT_f, zT_i

  (void)hipMemsetAsync(flags, 0, 32768, stream);
  cvt_x<<<16384, 256, 0, stream>>>((const float*)d_in[0], xh);
  cvt_w8<<<8192, 256, 0, stream>>>(w8, wg);
  pack8<<<8192, 256, 0, stream>>>(u8, ug);
  gemmz<<<4096, 256, 0, stream>>>(xh, wg, z01, z23);

  const unsigned short* zF = z01;
  const unsigned short* zI = z01 + 16777216;
  const unsigned short* zO = z23;
  const unsigned short* zC = z23 + 16777216;

  void* args[] = { (void*)&zF, (void*)&zI, (void*)&zO, (void*)&zC, (void*)&ug,
                   (void*)&bF, (void*)&bI, (void*)&bO, (void*)&bC,
                   (void*)&hh2, (void*)&flags, (void*)&outp };
  if (hipLaunchCooperativeKernel((const void*)lstm_rec, dim3(256), dim3(256), args, 0u, stream) != hipSuccess)
    lstm_rec<<<256, 256, 0, stream>>>(zF, zI, zO, zC, ug, bF, bI, bO, bC, hh2, flags, outp);

  expand_out<<<16384, 256, 0, stream>>>(hh2, outp);
}

// Round 15
// 1454.552 us; speedup vs baseline: 1.4144x; 1.0279x over previous
//
#include <hip/hip_runtime.h>

typedef float f32x4 __attribute__((ext_vector_type(4)));
typedef _Float16 f16x8 __attribute__((ext_vector_type(8)));
typedef _Float16 f16x4 __attribute__((ext_vector_type(4)));
typedef unsigned int u32x2 __attribute__((ext_vector_type(2)));

typedef const __attribute__((address_space(1))) unsigned int* gptr_t;
typedef __attribute__((address_space(3))) unsigned int* lptr_t;

__device__ __forceinline__ unsigned short f2h_u(float f){
  union { _Float16 h; unsigned short u; } cv; cv.h = (_Float16)f; return cv.u;
}
__device__ __forceinline__ float h2f(unsigned short u){
  union { unsigned short u; _Float16 h; } cv; cv.u = u; return (float)cv.h;
}
__device__ __forceinline__ float sigmoidf_(float x){ return 1.0f / (1.0f + __expf(-x)); }
__device__ __forceinline__ unsigned umax_(unsigned a, unsigned b){ return a > b ? a : b; }

// ---- poison-validated h loads: issue / wait+validate+retry / mfma ----
// piece i of chunk c: producers p0, p0+1; 8B each (4 cols at batch row)
#define ISSUEC(LO, HI, c)                                                      \
  _Pragma("unroll")                                                            \
  for (int i = 0; i < 8; ++i){                                                 \
    const int p0 = pbase + (c) * 16 + (i & 1) * 8;                             \
    const int ro = ((i >> 1) * 16 + r) * 4;                                    \
    const unsigned short* alo_ = hb2 + (size_t)p0 * 256 + ro;                  \
    const unsigned short* ahi_ = hb2 + (size_t)(p0 + 1) * 256 + ro;            \
    asm volatile("global_load_dwordx2 %0, %1, off sc0 sc1"                     \
                 : "=v"(LO[i]) : "v"(alo_) : "memory");                        \
    asm volatile("global_load_dwordx2 %0, %1, off sc0 sc1"                     \
                 : "=v"(HI[i]) : "v"(ahi_) : "memory");                        \
  }

#define WAITVALC(LO, HI, c)                                                    \
  for (;;){                                                                    \
    asm volatile("s_waitcnt vmcnt(0)" ::: "memory");                           \
    __builtin_amdgcn_sched_barrier(0);                                         \
    unsigned mx_ = 0;                                                          \
    _Pragma("unroll")                                                          \
    for (int i = 0; i < 8; ++i)                                                \
      mx_ = umax_(mx_, umax_(umax_(LO[i][0], LO[i][1]),                        \
                             umax_(HI[i][0], HI[i][1])));                      \
    if (__all(mx_ != 0xFFFFFFFFu)) break;                                      \
    ISSUEC(LO, HI, c);                                                         \
  }

#define COMPC2(LO, HI, c)                                                      \
  _Pragma("unroll")                                                            \
  for (int kk = 0; kk < 2; ++kk)                                               \
    _Pragma("unroll")                                                          \
    for (int nt = 0; nt < 2; ++nt)                                             \
      _Pragma("unroll")                                                        \
      for (int mt = 0; mt < 4; ++mt){                                          \
        const int i_ = mt * 2 + kk;                                            \
        f16x8 hf_ = __builtin_shufflevector(*(const f16x4*)&LO[i_],            \
                                            *(const f16x4*)&HI[i_],            \
                                            0, 1, 2, 3, 4, 5, 6, 7);           \
        acc[nt][mt] = __builtin_amdgcn_mfma_f32_16x16x32_f16(                  \
            uf[nt][(c) * 2 + kk], hf_, acc[nt][mt], 0, 0, 0);                  \
      }

// ---------- conversion: x (B,S,I) f32 -> (S,B,I) f16 ----------
__global__ __launch_bounds__(256) void cvt_x(const float* __restrict__ in,
                                             unsigned short* __restrict__ out){
  int idx = blockIdx.x * 256 + threadIdx.x;
  int d4 = idx * 4;
  int s = d4 >> 16, b = (d4 >> 10) & 63, k = d4 & 1023;
  const float4 v = *(const float4*)(in + (size_t)b * 262144 + (size_t)s * 1024 + k);
  ushort4 o;
  o.x = f2h_u(v.x); o.y = f2h_u(v.y); o.z = f2h_u(v.z); o.w = f2h_u(v.w);
  *(ushort4*)(out + d4) = o;
}

struct P8 { const float* p[8]; };

__global__ __launch_bounds__(256) void cvt_w8(P8 mats, unsigned short* __restrict__ out){
  int idx = blockIdx.x * 256 + threadIdx.x;
  int e = idx * 4;
  int mi = e >> 20, off = e & 1048575;
  const float4 v = *(const float4*)(mats.p[mi] + off);
  ushort4 o;
  o.x = f2h_u(v.x); o.y = f2h_u(v.y); o.z = f2h_u(v.z); o.w = f2h_u(v.w);
  *(ushort4*)(out + e) = o;
}

__global__ __launch_bounds__(256) void pack8(P8 mats, unsigned short* __restrict__ out){
  int idx = blockIdx.x * 256 + threadIdx.x;
  int e = idx * 4;
  int j = e >> 10, k = e & 1023;
  int m = j & 7, row = j >> 3;
  const float4 v = *(const float4*)(mats.p[m] + (size_t)row * 1024 + k);
  ushort4 o;
  o.x = f2h_u(v.x); o.y = f2h_u(v.y); o.z = f2h_u(v.z); o.w = f2h_u(v.w);
  *(ushort4*)(out + e) = o;
}

// ---------- m97-style dual-B masked-linear GEMM (round-14 validated) ----------
__global__ __launch_bounds__(256, 2) void gemmz(
    const unsigned short* __restrict__ Xh,
    const unsigned short* __restrict__ Wg,
    unsigned short* __restrict__ Z01,
    unsigned short* __restrict__ Z23){
  __shared__ unsigned short As[128 * 32];
  __shared__ unsigned short Bl[128 * 32];
  __shared__ unsigned short Bm[128 * 32];
  const int tid = threadIdx.x;
  const int wave = tid >> 6, lane = tid & 63;
  const int r = lane & 15, q = lane >> 4;
  const int bid0 = blockIdx.x;
  const int bid = (bid0 & 7) * 512 + (bid0 >> 3);
  const int m0 = (bid & 127) * 128;
  const int n0 = ((bid >> 7) & 7) * 128;
  const int g  = bid >> 10;
  const int wm = wave >> 1, wn = wave & 1;

  const unsigned short* WL = Wg + ((size_t)(2 * g) << 20);
  const unsigned short* WM = WL + (1u << 20);

  f32x4 accL[4][4], accM[4][4];
#pragma unroll
  for (int a = 0; a < 4; ++a)
#pragma unroll
    for (int b = 0; b < 4; ++b){ accL[a][b] = 0.f; accM[a][b] = 0.f; }

  const int st_rl = lane >> 2;
  const int st_s0 = lane & 3;

  for (int kt = 0; kt < 32; ++kt){
    const int k0 = kt * 32;
#pragma unroll
    for (int j = 0; j < 2; ++j){
      const int c = wave * 2 + j;
      const int row = c * 16 + st_rl;
      const int slot = st_s0 ^ ((row >> 1) & 3);
      const unsigned short* sA = Xh + (size_t)(m0 + row) * 1024 + k0 + slot * 8;
      const unsigned short* sL = WL + (size_t)(n0 + row) * 1024 + k0 + slot * 8;
      const unsigned short* sM = WM + (size_t)(n0 + row) * 1024 + k0 + slot * 8;
      __builtin_amdgcn_global_load_lds((gptr_t)sA, (lptr_t)(As + c * 512), 16, 0, 0);
      __builtin_amdgcn_global_load_lds((gptr_t)sL, (lptr_t)(Bl + c * 512), 16, 0, 0);
      __builtin_amdgcn_global_load_lds((gptr_t)sM, (lptr_t)(Bm + c * 512), 16, 0, 0);
    }
    __syncthreads();

    f16x8 af[4], bl[4], bm[4];
#pragma unroll
    for (int mt = 0; mt < 4; ++mt){
      const int row = wm * 64 + mt * 16 + r;
      const int slot = q ^ ((row >> 1) & 3);
      af[mt] = *(const f16x8*)(As + row * 32 + slot * 8);
    }
#pragma unroll
    for (int nt = 0; nt < 4; ++nt){
      const int row = wn * 64 + nt * 16 + r;
      const int slot = q ^ ((row >> 1) & 3);
      bl[nt] = *(const f16x8*)(Bl + row * 32 + slot * 8);
      bm[nt] = *(const f16x8*)(Bm + row * 32 + slot * 8);
    }
#pragma unroll
    for (int nt = 0; nt < 4; ++nt)
#pragma unroll
      for (int mt = 0; mt < 4; ++mt){
        accL[mt][nt] = __builtin_amdgcn_mfma_f32_16x16x32_f16(af[mt], bl[nt], accL[mt][nt], 0, 0, 0);
        accM[mt][nt] = __builtin_amdgcn_mfma_f32_16x16x32_f16(af[mt], bm[nt], accM[mt][nt], 0, 0, 0);
      }
    __syncthreads();
  }

  unsigned short* Zp = (g < 2) ? (Z01 + ((size_t)g << 24)) : (Z23 + ((size_t)(g - 2) << 24));
#pragma unroll
  for (int mt = 0; mt < 4; ++mt)
#pragma unroll
    for (int nt = 0; nt < 4; ++nt){
      f32x4 aL = accL[mt][nt], aM = accM[mt][nt];
      union { ushort4 u; uint2 d; } o;
      o.u.x = f2h_u(aL[0] * sigmoidf_(aM[0]));
      o.u.y = f2h_u(aL[1] * sigmoidf_(aM[1]));
      o.u.z = f2h_u(aL[2] * sigmoidf_(aM[2]));
      o.u.w = f2h_u(aL[3] * sigmoidf_(aM[3]));
      const int gn = n0 + wn * 64 + nt * 16 + r;
      const int gm = m0 + wm * 64 + mt * 16 + q * 4;
      *(uint2*)(Zp + (size_t)gn * 16384 + gm) = o.d;
    }
}

// ---------- recurrence: poison-validated data-flow sync (no flags) ----------
// hh2 pre-poisoned 0xFF. Producer: store h line write-through, no drain/flag.
// Consumer: sc0sc1 loads + umax poison check + retry = poll fused into load.
// One __syncthreads/step; part double-buffered by step parity.
__global__ __launch_bounds__(256, 1) void lstm_rec(
    const unsigned short* __restrict__ zF, const unsigned short* __restrict__ zI,
    const unsigned short* __restrict__ zO, const unsigned short* __restrict__ zC,
    const unsigned short* __restrict__ Ug,
    const float* __restrict__ bF, const float* __restrict__ bI,
    const float* __restrict__ bO, const float* __restrict__ bC,
    unsigned short* __restrict__ hh2,        // [256][256][64][4] f16, poisoned
    float* __restrict__ out){
  const int tid = threadIdx.x, wave = tid >> 6, lane = tid & 63;
  const int bi = blockIdx.x, n0 = bi * 4, j0 = bi * 32;
  const int r = lane & 15, q = lane >> 4;
  const int pbase = wave * 64 + 2 * q;
  __shared__ __align__(16) float part[2][4][64][36];

  f16x8 uf[2][8];
#pragma unroll
  for (int nt = 0; nt < 2; ++nt)
#pragma unroll
    for (int kk = 0; kk < 8; ++kk)
      uf[nt][kk] = *(const f16x8*)(Ug + (size_t)(j0 + nt * 16 + r) * 1024 + wave * 256 + kk * 32 + q * 8);

  const int cb = tid >> 2, cl = tid & 3;
  const float bFv = bF[n0 + cl], bIv = bI[n0 + cl], bOv = bO[n0 + cl], bCv = bC[n0 + cl];
  const size_t zb = (size_t)(n0 + cl) * 16384 + cb;
  float c_reg = 0.f;

#pragma unroll 1
  for (int s = 0; s < 256; ++s){
    float zf = h2f(zF[zb + s * 64]);
    float zi = h2f(zI[zb + s * 64]);
    float zo = h2f(zO[zb + s * 64]);
    float zc = h2f(zC[zb + s * 64]);

    f32x4 acc[2][4];
#pragma unroll
    for (int nt = 0; nt < 2; ++nt)
#pragma unroll
      for (int mt = 0; mt < 4; ++mt) acc[nt][mt] = 0.f;

    if (s > 0){
      const unsigned short* hb2 = hh2 + (size_t)(s - 1) * 65536;
      u32x2 Alo[8], Ahi[8], Blo[8], Bhi[8];
      ISSUEC(Alo, Ahi, 0);
      WAITVALC(Alo, Ahi, 0);
      ISSUEC(Blo, Bhi, 1);
      COMPC2(Alo, Ahi, 0);
      WAITVALC(Blo, Bhi, 1);
      ISSUEC(Alo, Ahi, 2);
      COMPC2(Blo, Bhi, 1);
      WAITVALC(Alo, Ahi, 2);
      ISSUEC(Blo, Bhi, 3);
      COMPC2(Alo, Ahi, 2);
      WAITVALC(Blo, Bhi, 3);
      COMPC2(Blo, Bhi, 3);
    }

    const int pp = s & 1;
#pragma unroll
    for (int nt = 0; nt < 2; ++nt)
#pragma unroll
      for (int mt = 0; mt < 4; ++mt)
        *(f32x4*)&part[pp][wave][mt * 16 + r][nt * 16 + q * 4] = acc[nt][mt];
    __syncthreads();

    f32x4 y0 = 0.f, y1 = 0.f;
#pragma unroll
    for (int w = 0; w < 4; ++w){
      y0 += *(const f32x4*)&part[pp][w][cb][cl * 8];
      y1 += *(const f32x4*)&part[pp][w][cb][cl * 8 + 4];
    }

    float fg = sigmoidf_(zf + y0[0] * sigmoidf_(y0[1]) + bFv);
    float ig = sigmoidf_(zi + y0[2] * sigmoidf_(y0[3]) + bIv);
    float og = sigmoidf_(zo + y1[0] * sigmoidf_(y1[1]) + bOv);
    float cg = tanhf   (zc + y1[2] * sigmoidf_(y1[3]) + bCv);
    c_reg = cg * ig + fg * c_reg;
    float h = og * c_reg;

    // producer store: packed pair, write-through LLC; data IS the flag
    float hn = __shfl_xor(h, 1);
    if (!(cl & 1)){
      unsigned int pv = (unsigned)f2h_u(h) | ((unsigned)f2h_u(hn) << 16);
      const unsigned short* hw = hh2 + (size_t)s * 65536 + bi * 256 + cb * 4 + cl;
      asm volatile("global_store_dword %0, %1, off sc0 sc1" :: "v"(hw), "v"(pv) : "memory");
    }
    if (s == 255){
      out[16777216 + cb * 1024 + n0 + cl] = h;
      out[16777216 + 65536 + cb * 1024 + n0 + cl] = c_reg;
    }
  }
}

// ---------- expand hh2 (producer-major) -> out (B,S,H f32) ----------
__global__ __launch_bounds__(256) void expand_out(const unsigned short* __restrict__ hh2,
                                                  float* __restrict__ out){
  int idx = blockIdx.x * 256 + threadIdx.x;
  int p = idx & 255, s = (idx >> 8) & 255, cb = idx >> 16;
  f16x4 v = *(const f16x4*)(hh2 + (size_t)s * 65536 + p * 256 + cb * 4);
  float4 f = { (float)v[0], (float)v[1], (float)v[2], (float)v[3] };
  *(float4*)(out + ((size_t)cb * 256 + s) * 1024 + p * 4) = f;
}

// ---------- host launch ----------
extern "C" void kernel_launch(void* const* d_in, const int* in_sizes, int n_in,
                              void* d_out, int out_size, void* d_ws, size_t ws_size,
                              hipStream_t stream){
  (void)in_sizes; (void)n_in; (void)out_size; (void)ws_size;
  char* ws = (char*)d_ws;
  const float* bF = (const float*)d_in[17];
  const float* bI = (const float*)d_in[18];
  const float* bO = (const float*)d_in[19];
  const float* bC = (const float*)d_in[20];
  float* outp = (float*)d_out;
  P8 w8, u8;
  for (int m = 0; m < 8; ++m){
    w8.p[m] = (const float*)d_in[1 + m];
    u8.p[m] = (const float*)d_in[9 + m];
  }

  unsigned short* xh  = (unsigned short*)(ws);               // 33,554,432 B
  unsigned short* wg  = (unsigned short*)(ws + 33554432);    // 16,777,216 B
  unsigned short* ug  = (unsigned short*)(ws + 50331648);    // 16,777,216 B
  unsigned short* z23 = (unsigned short*)(ws + 67108864);    // 67,108,864 B
  unsigned short* hh2 = (unsigned short*)(ws + 134217728);   // 33,554,432 B
  unsigned short* z01 = (unsigned short*)d_out;              // zT_f, zT_i

  (void)hipMemsetAsync(hh2, 0xFF, 33554432, stream);   // poison all h slots
  cvt_x<<<16384, 256, 0, stream>>>((const float*)d_in[0], xh);
  cvt_w8<<<8192, 256, 0, stream>>>(w8, wg);
  pack8<<<8192, 256, 0, stream>>>(u8, ug);
  gemmz<<<4096, 256, 0, stream>>>(xh, wg, z01, z23);

  const unsigned short* zF = z01;
  const unsigned short* zI = z01 + 16777216;
  const unsigned short* zO = z23;
  const unsigned short* zC = z23 + 16777216;

  void* args[] = { (void*)&zF, (void*)&zI, (void*)&zO, (void*)&zC, (void*)&ug,
                   (void*)&bF, (void*)&bI, (void*)&bO, (void*)&bC,
                   (void*)&hh2, (void*)&outp };
  if (hipLaunchCooperativeKernel((const void*)lstm_rec, dim3(256), dim3(256), args, 0u, stream) != hipSuccess)
    lstm_rec<<<256, 256, 0, stream>>>(zF, zI, zO, zC, ug, bF, bI, bO, bC, hh2, outp);

  expand_out<<<16384, 256, 0, stream>>>(hh2, outp);
}